// Round 1
// baseline (673.391 us; speedup 1.0000x reference)
//
#include <hip/hip_runtime.h>

#define B_    4096
#define IN_   1024
#define H_    1024
#define G4H   4096
#define NLAY  4

#define BM    128
#define BK    64
#define NT    512

typedef __attribute__((ext_vector_type(8))) short bf16x8;
typedef __attribute__((ext_vector_type(4))) float f32x4;

__device__ __forceinline__ unsigned short f2bf(float f) {
  unsigned u = __builtin_bit_cast(unsigned, f);
  u += 0x7FFFu + ((u >> 16) & 1u);          // round-to-nearest-even
  return (unsigned short)(u >> 16);
}

// LDS layout: [row][k] bf16, row length BK=64 (128 B). XOR swizzle to kill
// the 128B-stride bank conflict on ds_read_b128 (guide §6 G4).
__device__ __forceinline__ int swz(int row, int kelem) {
  return ((row * BK + kelem) * 2) ^ ((row & 7) << 4);
}

__device__ __forceinline__ float fast_sigmoid(float x) {
  float e = __expf(-fabsf(x));
  float s = 1.0f / (1.0f + e);
  return x >= 0.0f ? s : 1.0f - s;
}
__device__ __forceinline__ float fast_tanh(float x) {
  float e = __expf(-2.0f * fabsf(x));
  float t = (1.0f - e) / (1.0f + e);
  return x >= 0.0f ? t : -t;
}

// stage 128x64 fp32 activations -> bf16 LDS tile (reg-staged conversion)
__device__ __forceinline__ void stage_a(char* sA, const float* __restrict__ Asrc) {
  const int tid = threadIdx.x;
  const int r  = tid >> 2;
  const int kq = (tid & 3) << 4;
  const float* p = Asrc + (size_t)r * 1024 + kq;
  f32x4 v0 = ((const f32x4*)p)[0];
  f32x4 v1 = ((const f32x4*)p)[1];
  f32x4 v2 = ((const f32x4*)p)[2];
  f32x4 v3 = ((const f32x4*)p)[3];
  bf16x8 o0, o1;
#pragma unroll
  for (int j = 0; j < 4; ++j) {
    o0[j]     = (short)f2bf(v0[j]);
    o0[4 + j] = (short)f2bf(v1[j]);
    o1[j]     = (short)f2bf(v2[j]);
    o1[4 + j] = (short)f2bf(v3[j]);
  }
  *(bf16x8*)(sA + swz(r, kq))     = o0;
  *(bf16x8*)(sA + swz(r, kq + 8)) = o1;
}

#define GLDS16(gsrc, ldst)                                                  \
  __builtin_amdgcn_global_load_lds(                                         \
      (__attribute__((address_space(1))) void*)(gsrc),                      \
      (__attribute__((address_space(3))) void*)(ldst), 16, 0, 0)

// ---------------------------------------------------------------------------
// Fused LSTM layer: gates = [x|h_prev] @ [Wi;Wh] + bi + bh, then cell update.
// Block: 128 rows x 64 h-cols (= 4 gate tiles of 128x64). 8 waves (2x4).
// Wave tile: 64 rows x 16 h-cols x 4 gates. Acc: 4 gates x 4 Mfrags x f32x4.
// ---------------------------------------------------------------------------
template <bool PRET>
__global__ __launch_bounds__(NT) void lstm_layer(
    const float* __restrict__ xin, const float* __restrict__ hprev,
    const float* __restrict__ cprev, const float* __restrict__ Wi,
    const float* __restrict__ Wh, const float* __restrict__ bi,
    const float* __restrict__ bh, const unsigned short* __restrict__ wt,
    float* __restrict__ hout, float* __restrict__ cout) {
  __shared__ char sA[BM * BK * 2];          // 16 KB
  __shared__ char sB[256 * BK * 2];         // 32 KB  (256 gate-cols)

  const int tid  = threadIdx.x;
  const int lane = tid & 63;
  const int wid  = tid >> 6;
  const int wm   = wid >> 2;      // 0..1
  const int wn   = wid & 3;       // 0..3
  const int bm   = blockIdx.x;    // 0..31
  const int bn   = blockIdx.y;    // 0..15

  f32x4 acc[4][4];
#pragma unroll
  for (int g = 0; g < 4; ++g)
#pragma unroll
    for (int m = 0; m < 4; ++m) acc[g][m] = (f32x4){0.f, 0.f, 0.f, 0.f};

  // fallback B-staging coords
  const int bc   = tid & 255;                              // lds col 0..255
  const int bkh  = (tid >> 8) * 32;                        // k half
  const int gcol = (bc >> 6) * 1024 + bn * 64 + (bc & 63); // global gate col

  for (int ks = 0; ks < 2048 / BK; ++ks) {
    const int k0 = ks * BK;
    __syncthreads();
    // ---- stage B ----
    if constexpr (PRET) {
      const unsigned short* tile = wt + (size_t)(bn * 32 + ks) * 16384;
#pragma unroll
      for (int rd = 0; rd < 4; ++rd) {
        GLDS16(tile + (rd * 512 + tid) * 8, sB + rd * 8192 + wid * 1024);
      }
    } else {
      const float* Bsrc =
          (k0 < IN_) ? (Wi + (size_t)k0 * G4H) : (Wh + (size_t)(k0 - IN_) * G4H);
      float v[32];
#pragma unroll
      for (int kk = 0; kk < 32; ++kk)
        v[kk] = Bsrc[(size_t)(bkh + kk) * G4H + gcol];
#pragma unroll
      for (int oct = 0; oct < 4; ++oct) {
        bf16x8 o;
#pragma unroll
        for (int j = 0; j < 8; ++j) o[j] = (short)f2bf(v[oct * 8 + j]);
        *(bf16x8*)(sB + swz(bc, bkh + oct * 8)) = o;
      }
    }
    // ---- stage A (overlaps with B DMA) ----
    {
      const float* Asrc = (k0 < IN_)
                              ? (xin + (size_t)(bm * BM) * IN_ + k0)
                              : (hprev + (size_t)(bm * BM) * H_ + (k0 - IN_));
      stage_a(sA, Asrc);
    }
    __syncthreads();
    // ---- MFMA ----
#pragma unroll
    for (int kk = 0; kk < BK; kk += 32) {
      const int ke = kk + (lane >> 4) * 8;
      bf16x8 a[4], b[4];
#pragma unroll
      for (int m = 0; m < 4; ++m)
        a[m] = *(const bf16x8*)(sA + swz(wm * 64 + m * 16 + (lane & 15), ke));
#pragma unroll
      for (int g = 0; g < 4; ++g)
        b[g] = *(const bf16x8*)(sB + swz(g * 64 + wn * 16 + (lane & 15), ke));
#pragma unroll
      for (int g = 0; g < 4; ++g)
#pragma unroll
        for (int m = 0; m < 4; ++m)
          acc[g][m] = __builtin_amdgcn_mfma_f32_16x16x32_bf16(a[m], b[g],
                                                              acc[g][m], 0, 0, 0);
    }
  }

  // ---- LSTM cell epilogue (all 4 gates register-local) ----
  const int hcol = bn * 64 + wn * 16 + (lane & 15);
  float bsum[4];
#pragma unroll
  for (int g = 0; g < 4; ++g)
    bsum[g] = bi[g * 1024 + hcol] + bh[g * 1024 + hcol];
#pragma unroll
  for (int m = 0; m < 4; ++m) {
    const int row0 = bm * BM + wm * 64 + m * 16 + ((lane >> 4) << 2);
#pragma unroll
    for (int r = 0; r < 4; ++r) {
      const int row = row0 + r;
      const float gi = fast_sigmoid(acc[0][m][r] + bsum[0]);
      const float gf = fast_sigmoid(acc[1][m][r] + bsum[1]);
      const float gg = fast_tanh(acc[2][m][r] + bsum[2]);
      const float go = fast_sigmoid(acc[3][m][r] + bsum[3]);
      const float cp = cprev[(size_t)row * H_ + hcol];
      const float c  = gf * cp + gi * gg;
      const float h  = go * fast_tanh(c);
      cout[(size_t)row * H_ + hcol] = c;
      hout[(size_t)row * H_ + hcol] = h;
    }
  }
}

// ---------------------------------------------------------------------------
// FC: y = h3 @ fc_W + fc_b   (M=4096, N=1024, K=1024)
// ---------------------------------------------------------------------------
template <bool PRET>
__global__ __launch_bounds__(NT) void fc_kernel(
    const float* __restrict__ hin, const float* __restrict__ W,
    const unsigned short* __restrict__ wt, const float* __restrict__ bias,
    float* __restrict__ y) {
  __shared__ char sA[BM * BK * 2];   // 16 KB
  __shared__ char sB[64 * BK * 2];   // 8 KB
  const int tid  = threadIdx.x;
  const int lane = tid & 63;
  const int wid  = tid >> 6;
  const int wm   = wid >> 2;
  const int wn   = wid & 3;
  const int bm   = blockIdx.x;   // 0..31
  const int bn   = blockIdx.y;   // 0..15

  f32x4 acc[4];
#pragma unroll
  for (int m = 0; m < 4; ++m) acc[m] = (f32x4){0.f, 0.f, 0.f, 0.f};

  const int bc  = tid & 63;
  const int bko = (tid >> 6) * 8;

  for (int ks = 0; ks < 1024 / BK; ++ks) {
    const int k0 = ks * BK;
    __syncthreads();
    if constexpr (PRET) {
      const unsigned short* tile = wt + (size_t)(bn * 16 + ks) * 4096;
      GLDS16(tile + tid * 8, sB + wid * 1024);
    } else {
      float v[8];
#pragma unroll
      for (int j = 0; j < 8; ++j)
        v[j] = W[(size_t)(k0 + bko + j) * 1024 + bn * 64 + bc];
      bf16x8 o;
#pragma unroll
      for (int j = 0; j < 8; ++j) o[j] = (short)f2bf(v[j]);
      *(bf16x8*)(sB + swz(bc, bko)) = o;
    }
    stage_a(sA, hin + (size_t)(bm * BM) * 1024 + k0);
    __syncthreads();
#pragma unroll
    for (int kk = 0; kk < BK; kk += 32) {
      const int ke = kk + (lane >> 4) * 8;
      bf16x8 a[4];
#pragma unroll
      for (int m = 0; m < 4; ++m)
        a[m] = *(const bf16x8*)(sA + swz(wm * 64 + m * 16 + (lane & 15), ke));
      bf16x8 b = *(const bf16x8*)(sB + swz(wn * 16 + (lane & 15), ke));
#pragma unroll
      for (int m = 0; m < 4; ++m)
        acc[m] = __builtin_amdgcn_mfma_f32_16x16x32_bf16(a[m], b, acc[m], 0, 0, 0);
    }
  }
  const int col = bn * 64 + wn * 16 + (lane & 15);
  const float bb = bias[col];
#pragma unroll
  for (int m = 0; m < 4; ++m) {
    const int row0 = bm * BM + wm * 64 + m * 16 + ((lane >> 4) << 2);
#pragma unroll
    for (int r = 0; r < 4; ++r)
      y[(size_t)(row0 + r) * 1024 + col] = acc[m][r] + bb;
  }
}

// ---------------------------------------------------------------------------
// Weight pre-transpose+convert: write exact swizzled LDS tile images (bf16)
// so GEMM B-staging is a linear global_load_lds copy.
// ---------------------------------------------------------------------------
__global__ __launch_bounds__(NT) void transposeW(const float* __restrict__ Wi,
                                                 const float* __restrict__ Wh,
                                                 unsigned short* __restrict__ wt) {
  const int bn = blockIdx.x;   // 0..15
  const int ks = blockIdx.y;   // 0..31
  const int l  = blockIdx.z;   // 0..3
  const int tid = threadIdx.x;
  const int c  = tid & 255;
  const int kh = (tid >> 8) * 32;
  const int gcol = (c >> 6) * 1024 + bn * 64 + (c & 63);
  const int k0 = ks * 64;
  const float* src = (k0 < 1024)
                         ? (Wi + (size_t)l * 1024 * 4096 + (size_t)k0 * 4096)
                         : (Wh + (size_t)l * 1024 * 4096 + (size_t)(k0 - 1024) * 4096);
  unsigned short* tile = wt + (((size_t)l * 16 + bn) * 32 + ks) * 16384;
  float v[32];
#pragma unroll
  for (int kk = 0; kk < 32; ++kk)
    v[kk] = src[(size_t)(kh + kk) * 4096 + gcol];
#pragma unroll
  for (int oct = 0; oct < 4; ++oct) {
    bf16x8 o;
#pragma unroll
    for (int j = 0; j < 8; ++j) o[j] = (short)f2bf(v[oct * 8 + j]);
    *(bf16x8*)((char*)tile + swz(c, kh + oct * 8)) = o;
  }
}

__global__ __launch_bounds__(NT) void transposeFc(const float* __restrict__ W,
                                                  unsigned short* __restrict__ wt) {
  const int bn = blockIdx.x;   // 0..15
  const int ks = blockIdx.y;   // 0..15
  const int tid = threadIdx.x;
  const int c  = tid & 63;
  const int ko = (tid >> 6) * 8;
  float v[8];
#pragma unroll
  for (int j = 0; j < 8; ++j)
    v[j] = W[(size_t)(ks * 64 + ko + j) * 1024 + bn * 64 + c];
  bf16x8 o;
#pragma unroll
  for (int j = 0; j < 8; ++j) o[j] = (short)f2bf(v[j]);
  unsigned short* tile = wt + ((size_t)bn * 16 + ks) * 4096;
  *(bf16x8*)((char*)tile + swz(c, ko)) = o;
}

extern "C" void kernel_launch(void* const* d_in, const int* in_sizes, int n_in,
                              void* d_out, int out_size, void* d_ws,
                              size_t ws_size, hipStream_t stream) {
  const float* x     = (const float*)d_in[0];
  const float* hprev = (const float*)d_in[1];
  const float* cprev = (const float*)d_in[2];
  const float* Wi    = (const float*)d_in[3];
  const float* Wh    = (const float*)d_in[4];
  const float* bi    = (const float*)d_in[5];
  const float* bh    = (const float*)d_in[6];
  const float* fcW   = (const float*)d_in[7];
  const float* fcb   = (const float*)d_in[8];

  float* out = (float*)d_out;
  const size_t BH = (size_t)B_ * H_;          // 4194304
  float* y    = out;
  float* hout = out + BH;
  float* cout = out + 5 * BH;

  const size_t WT_ELEMS = (size_t)4 * 16 * 32 * 16384;  // 33554432 bf16
  const size_t FC_ELEMS = (size_t)16 * 16 * 4096;       // 1048576 bf16
  const bool pret = ws_size >= (WT_ELEMS + FC_ELEMS) * 2;
  unsigned short* wt   = (unsigned short*)d_ws;
  unsigned short* fcwt = wt + WT_ELEMS;

  dim3 blk(NT);
  if (pret) {
    transposeW<<<dim3(16, 32, 4), blk, 0, stream>>>(Wi, Wh, wt);
    transposeFc<<<dim3(16, 16), blk, 0, stream>>>(fcW, fcwt);
  }

  dim3 grid(32, 16);
  for (int l = 0; l < NLAY; ++l) {
    const float* xin = (l == 0) ? x : (hout + (size_t)(l - 1) * BH);
    const unsigned short* wtl = wt + (size_t)l * 16 * 32 * 16384;
    if (pret)
      lstm_layer<true><<<grid, blk, 0, stream>>>(
          xin, hprev + (size_t)l * BH, cprev + (size_t)l * BH,
          Wi + (size_t)l * 1024 * 4096, Wh + (size_t)l * 1024 * 4096,
          bi + l * 4096, bh + l * 4096, wtl, hout + (size_t)l * BH,
          cout + (size_t)l * BH);
    else
      lstm_layer<false><<<grid, blk, 0, stream>>>(
          xin, hprev + (size_t)l * BH, cprev + (size_t)l * BH,
          Wi + (size_t)l * 1024 * 4096, Wh + (size_t)l * 1024 * 4096,
          bi + l * 4096, bh + l * 4096, nullptr, hout + (size_t)l * BH,
          cout + (size_t)l * BH);
  }
  if (pret)
    fc_kernel<true><<<grid, blk, 0, stream>>>(hout + 3 * BH, fcW, fcwt, fcb, y);
  else
    fc_kernel<false><<<grid, blk, 0, stream>>>(hout + 3 * BH, fcW, nullptr, fcb, y);
}

// Round 2
// 628.585 us; speedup vs baseline: 1.0713x; 1.0713x over previous
//
#include <hip/hip_runtime.h>

#define B_    4096
#define IN_   1024
#define H_    1024
#define G4H   4096
#define NLAY  4

#define BM    128
#define BK    64
#define NT    512

typedef __attribute__((ext_vector_type(8))) short bf16x8;
typedef __attribute__((ext_vector_type(4))) float f32x4;

__device__ __forceinline__ unsigned short f2bf(float f) {
  unsigned u = __builtin_bit_cast(unsigned, f);
  u += 0x7FFFu + ((u >> 16) & 1u);          // round-to-nearest-even
  return (unsigned short)(u >> 16);
}

// LDS layout: [row][k] bf16, row length BK=64 (128 B). XOR swizzle kills the
// 128B-stride bank conflict on ds_read_b128. Slot s of row r holds k-octet
// j = s ^ (r&7)  (16B granules are never split).
__device__ __forceinline__ int swz(int row, int kelem) {
  return ((row * BK + kelem) * 2) ^ ((row & 7) << 4);
}

__device__ __forceinline__ float fast_sigmoid(float x) {
  float e = __expf(-fabsf(x));
  float s = 1.0f / (1.0f + e);
  return x >= 0.0f ? s : 1.0f - s;
}
__device__ __forceinline__ float fast_tanh(float x) {
  float e = __expf(-2.0f * fabsf(x));
  float t = (1.0f - e) / (1.0f + e);
  return x >= 0.0f ? t : -t;
}

// stage 128x64 fp32 activations -> bf16 LDS tile (reg-staged conversion)
// (fallback path only)
__device__ __forceinline__ void stage_a(char* sA, const float* __restrict__ Asrc) {
  const int tid = threadIdx.x;
  const int r  = tid >> 2;
  const int kq = (tid & 3) << 4;
  const float* p = Asrc + (size_t)r * 1024 + kq;
  f32x4 v0 = ((const f32x4*)p)[0];
  f32x4 v1 = ((const f32x4*)p)[1];
  f32x4 v2 = ((const f32x4*)p)[2];
  f32x4 v3 = ((const f32x4*)p)[3];
  bf16x8 o0, o1;
#pragma unroll
  for (int j = 0; j < 4; ++j) {
    o0[j]     = (short)f2bf(v0[j]);
    o0[4 + j] = (short)f2bf(v1[j]);
    o1[j]     = (short)f2bf(v2[j]);
    o1[4 + j] = (short)f2bf(v3[j]);
  }
  *(bf16x8*)(sA + swz(r, kq))     = o0;
  *(bf16x8*)(sA + swz(r, kq + 8)) = o1;
}

#define GLDS16(gsrc, ldst)                                                  \
  __builtin_amdgcn_global_load_lds(                                         \
      (__attribute__((address_space(1))) void*)(gsrc),                      \
      (__attribute__((address_space(3))) void*)(ldst), 16, 0, 0)

// ---------------------------------------------------------------------------
// Fused LSTM layer. MODE: 2 = bf16 A via global_load_lds (full),
// 1 = pre-transposed weights, fp32 A reg-staged, 0 = everything from fp32.
// Block: 128 rows x 64 h-cols (4 gate tiles). 8 waves (2x4).
// ---------------------------------------------------------------------------
template <int MODE>
__global__ __launch_bounds__(NT) void lstm_layer(
    const float* __restrict__ xin, const float* __restrict__ hprev,
    const float* __restrict__ cprev, const float* __restrict__ Wi,
    const float* __restrict__ Wh, const float* __restrict__ bi,
    const float* __restrict__ bh, const unsigned short* __restrict__ wt,
    const unsigned short* __restrict__ aX, const unsigned short* __restrict__ aH,
    float* __restrict__ hout, float* __restrict__ cout,
    unsigned short* __restrict__ hbfout) {
  __shared__ char sA[BM * BK * 2];          // 16 KB
  __shared__ char sB[256 * BK * 2];         // 32 KB

  const int tid  = threadIdx.x;
  const int lane = tid & 63;
  const int wid  = tid >> 6;
  const int wm   = wid >> 2;      // 0..1
  const int wn   = wid & 3;       // 0..3
  // XCD-chunked bijective swizzle: 512 blocks = 8 XCDs x 64
  const int bid  = (blockIdx.x & 7) * 64 + (blockIdx.x >> 3);
  const int bm   = bid & 31;
  const int bn   = bid >> 5;

  f32x4 acc[4][4];
#pragma unroll
  for (int g = 0; g < 4; ++g)
#pragma unroll
    for (int m = 0; m < 4; ++m) acc[g][m] = (f32x4){0.f, 0.f, 0.f, 0.f};

  // MODE==2: per-lane pre-swizzled global source for A
  const unsigned short* aSrcX = nullptr;
  const unsigned short* aSrcH = nullptr;
  if constexpr (MODE == 2) {
    const int rloc = wid * 8 + (lane >> 3);            // rows 0..63 (call 0)
    const int jA   = (lane & 7) ^ ((lane >> 3) & 7);   // octet for this slot
    const size_t lo = (size_t)(bm * BM + rloc) * 1024 + jA * 8;
    aSrcX = aX + lo;
    aSrcH = aH + lo;
  }

  // fallback B-staging coords
  const int bc   = tid & 255;
  const int bkh  = (tid >> 8) * 32;
  const int gcol = (bc >> 6) * 1024 + bn * 64 + (bc & 63);

  for (int ks = 0; ks < 2048 / BK; ++ks) {
    const int k0 = ks * BK;
    __syncthreads();
    // ---- stage B ----
    if constexpr (MODE >= 1) {
      const unsigned short* tile = wt + (size_t)(bn * 32 + ks) * 16384;
#pragma unroll
      for (int rd = 0; rd < 4; ++rd)
        GLDS16(tile + (rd * 512 + tid) * 8, sB + rd * 8192 + wid * 1024);
    } else {
      const float* Bsrc =
          (k0 < IN_) ? (Wi + (size_t)k0 * G4H) : (Wh + (size_t)(k0 - IN_) * G4H);
      float v[32];
#pragma unroll
      for (int kk = 0; kk < 32; ++kk)
        v[kk] = Bsrc[(size_t)(bkh + kk) * G4H + gcol];
#pragma unroll
      for (int oct = 0; oct < 4; ++oct) {
        bf16x8 o;
#pragma unroll
        for (int j = 0; j < 8; ++j) o[j] = (short)f2bf(v[oct * 8 + j]);
        *(bf16x8*)(sB + swz(bc, bkh + oct * 8)) = o;
      }
    }
    // ---- stage A ----
    if constexpr (MODE == 2) {
      const unsigned short* s = (ks < 16) ? aSrcX : aSrcH;
      const int off = (ks & 15) * 64;
      GLDS16(s + off,             sA + wid * 1024);          // rows 0..63
      GLDS16(s + off + 64 * 1024, sA + 8192 + wid * 1024);   // rows 64..127
    } else {
      const float* Asrc = (k0 < IN_)
                              ? (xin + (size_t)(bm * BM) * IN_ + k0)
                              : (hprev + (size_t)(bm * BM) * H_ + (k0 - IN_));
      stage_a(sA, Asrc);
    }
    __syncthreads();
    // ---- MFMA ----
#pragma unroll
    for (int kk = 0; kk < BK; kk += 32) {
      const int ke = kk + (lane >> 4) * 8;
      bf16x8 a[4], b[4];
#pragma unroll
      for (int m = 0; m < 4; ++m)
        a[m] = *(const bf16x8*)(sA + swz(wm * 64 + m * 16 + (lane & 15), ke));
#pragma unroll
      for (int g = 0; g < 4; ++g)
        b[g] = *(const bf16x8*)(sB + swz(g * 64 + wn * 16 + (lane & 15), ke));
#pragma unroll
      for (int g = 0; g < 4; ++g)
#pragma unroll
        for (int m = 0; m < 4; ++m)
          acc[g][m] = __builtin_amdgcn_mfma_f32_16x16x32_bf16(a[m], b[g],
                                                              acc[g][m], 0, 0, 0);
    }
  }

  // ---- LSTM cell epilogue ----
  const int hcol = bn * 64 + wn * 16 + (lane & 15);
  float bsum[4];
#pragma unroll
  for (int g = 0; g < 4; ++g)
    bsum[g] = bi[g * 1024 + hcol] + bh[g * 1024 + hcol];
#pragma unroll
  for (int m = 0; m < 4; ++m) {
    const int row0 = bm * BM + wm * 64 + m * 16 + ((lane >> 4) << 2);
#pragma unroll
    for (int r = 0; r < 4; ++r) {
      const int row = row0 + r;
      const float gi = fast_sigmoid(acc[0][m][r] + bsum[0]);
      const float gf = fast_sigmoid(acc[1][m][r] + bsum[1]);
      const float gg = fast_tanh(acc[2][m][r] + bsum[2]);
      const float go = fast_sigmoid(acc[3][m][r] + bsum[3]);
      const float cp = cprev[(size_t)row * H_ + hcol];
      const float c  = gf * cp + gi * gg;
      const float h  = go * fast_tanh(c);
      cout[(size_t)row * H_ + hcol] = c;
      hout[(size_t)row * H_ + hcol] = h;
      if constexpr (MODE == 2)
        hbfout[(size_t)row * H_ + hcol] = f2bf(h);
    }
  }
}

// ---------------------------------------------------------------------------
// FC: y = h3 @ fc_W + fc_b   (M=4096, N=1024, K=1024)
// ---------------------------------------------------------------------------
template <int MODE>
__global__ __launch_bounds__(NT) void fc_kernel(
    const float* __restrict__ hin, const float* __restrict__ W,
    const unsigned short* __restrict__ wt, const unsigned short* __restrict__ abf,
    const float* __restrict__ bias, float* __restrict__ y) {
  __shared__ char sA[BM * BK * 2];   // 16 KB
  __shared__ char sB[64 * BK * 2];   // 8 KB
  const int tid  = threadIdx.x;
  const int lane = tid & 63;
  const int wid  = tid >> 6;
  const int wm   = wid >> 2;
  const int wn   = wid & 3;
  const int bid  = (blockIdx.x & 7) * 64 + (blockIdx.x >> 3);
  const int bm   = bid & 31;
  const int bn   = bid >> 5;

  f32x4 acc[4];
#pragma unroll
  for (int m = 0; m < 4; ++m) acc[m] = (f32x4){0.f, 0.f, 0.f, 0.f};

  const unsigned short* aSrc = nullptr;
  if constexpr (MODE == 2) {
    const int rloc = wid * 8 + (lane >> 3);
    const int jA   = (lane & 7) ^ ((lane >> 3) & 7);
    aSrc = abf + (size_t)(bm * BM + rloc) * 1024 + jA * 8;
  }

  const int bc  = tid & 63;
  const int bko = (tid >> 6) * 8;

  for (int ks = 0; ks < 1024 / BK; ++ks) {
    const int k0 = ks * BK;
    __syncthreads();
    if constexpr (MODE >= 1) {
      const unsigned short* tile = wt + (size_t)(bn * 16 + ks) * 4096;
      GLDS16(tile + tid * 8, sB + wid * 1024);
    } else {
      float v[8];
#pragma unroll
      for (int j = 0; j < 8; ++j)
        v[j] = W[(size_t)(k0 + bko + j) * 1024 + bn * 64 + bc];
      bf16x8 o;
#pragma unroll
      for (int j = 0; j < 8; ++j) o[j] = (short)f2bf(v[j]);
      *(bf16x8*)(sB + swz(bc, bko)) = o;
    }
    if constexpr (MODE == 2) {
      const int off = ks * 64;
      GLDS16(aSrc + off,             sA + wid * 1024);
      GLDS16(aSrc + off + 64 * 1024, sA + 8192 + wid * 1024);
    } else {
      stage_a(sA, hin + (size_t)(bm * BM) * 1024 + k0);
    }
    __syncthreads();
#pragma unroll
    for (int kk = 0; kk < BK; kk += 32) {
      const int ke = kk + (lane >> 4) * 8;
      bf16x8 a[4];
#pragma unroll
      for (int m = 0; m < 4; ++m)
        a[m] = *(const bf16x8*)(sA + swz(wm * 64 + m * 16 + (lane & 15), ke));
      bf16x8 b = *(const bf16x8*)(sB + swz(wn * 16 + (lane & 15), ke));
#pragma unroll
      for (int m = 0; m < 4; ++m)
        acc[m] = __builtin_amdgcn_mfma_f32_16x16x32_bf16(a[m], b, acc[m], 0, 0, 0);
    }
  }
  const int col = bn * 64 + wn * 16 + (lane & 15);
  const float bb = bias[col];
#pragma unroll
  for (int m = 0; m < 4; ++m) {
    const int row0 = bm * BM + wm * 64 + m * 16 + ((lane >> 4) << 2);
#pragma unroll
    for (int r = 0; r < 4; ++r)
      y[(size_t)(row0 + r) * 1024 + col] = acc[m][r] + bb;
  }
}

// ---------------------------------------------------------------------------
// Weight pre-transpose+convert: swizzled LDS tile images (bf16).
// ---------------------------------------------------------------------------
__global__ __launch_bounds__(NT) void transposeW(const float* __restrict__ Wi,
                                                 const float* __restrict__ Wh,
                                                 unsigned short* __restrict__ wt) {
  const int bn = blockIdx.x;   // 0..15
  const int ks = blockIdx.y;   // 0..31
  const int l  = blockIdx.z;   // 0..3
  const int tid = threadIdx.x;
  const int c  = tid & 255;
  const int kh = (tid >> 8) * 32;
  const int gcol = (c >> 6) * 1024 + bn * 64 + (c & 63);
  const int k0 = ks * 64;
  const float* src = (k0 < 1024)
                         ? (Wi + (size_t)l * 1024 * 4096 + (size_t)k0 * 4096)
                         : (Wh + (size_t)l * 1024 * 4096 + (size_t)(k0 - 1024) * 4096);
  unsigned short* tile = wt + (((size_t)l * 16 + bn) * 32 + ks) * 16384;
  float v[32];
#pragma unroll
  for (int kk = 0; kk < 32; ++kk)
    v[kk] = src[(size_t)(kh + kk) * 4096 + gcol];
#pragma unroll
  for (int oct = 0; oct < 4; ++oct) {
    bf16x8 o;
#pragma unroll
    for (int j = 0; j < 8; ++j) o[j] = (short)f2bf(v[oct * 8 + j]);
    *(bf16x8*)((char*)tile + swz(c, kh + oct * 8)) = o;
  }
}

__global__ __launch_bounds__(NT) void transposeFc(const float* __restrict__ W,
                                                  unsigned short* __restrict__ wt) {
  const int bn = blockIdx.x;   // 0..15
  const int ks = blockIdx.y;   // 0..15
  const int tid = threadIdx.x;
  const int c  = tid & 63;
  const int ko = (tid >> 6) * 8;
  float v[8];
#pragma unroll
  for (int j = 0; j < 8; ++j)
    v[j] = W[(size_t)(ks * 64 + ko + j) * 1024 + bn * 64 + c];
  bf16x8 o;
#pragma unroll
  for (int j = 0; j < 8; ++j) o[j] = (short)f2bf(v[j]);
  unsigned short* tile = wt + ((size_t)bn * 16 + ks) * 4096;
  *(bf16x8*)((char*)tile + swz(c, ko)) = o;
}

// fp32 -> bf16 bulk convert (8 elements/thread)
__global__ __launch_bounds__(256) void cvt_bf16(const float* __restrict__ s,
                                                unsigned short* __restrict__ d,
                                                int n8) {
  const int i = blockIdx.x * 256 + threadIdx.x;
  if (i >= n8) return;
  const float* p = s + (size_t)i * 8;
  f32x4 a = ((const f32x4*)p)[0];
  f32x4 b = ((const f32x4*)p)[1];
  bf16x8 o;
#pragma unroll
  for (int j = 0; j < 4; ++j) {
    o[j]     = (short)f2bf(a[j]);
    o[4 + j] = (short)f2bf(b[j]);
  }
  *(bf16x8*)(d + (size_t)i * 8) = o;
}

extern "C" void kernel_launch(void* const* d_in, const int* in_sizes, int n_in,
                              void* d_out, int out_size, void* d_ws,
                              size_t ws_size, hipStream_t stream) {
  const float* x     = (const float*)d_in[0];
  const float* hprev = (const float*)d_in[1];
  const float* cprev = (const float*)d_in[2];
  const float* Wi    = (const float*)d_in[3];
  const float* Wh    = (const float*)d_in[4];
  const float* bi    = (const float*)d_in[5];
  const float* bh    = (const float*)d_in[6];
  const float* fcW   = (const float*)d_in[7];
  const float* fcb   = (const float*)d_in[8];

  float* out = (float*)d_out;
  const size_t BH = (size_t)B_ * H_;          // 4194304
  float* y    = out;
  float* hout = out + BH;
  float* cout = out + 5 * BH;

  const size_t WT_ELEMS = (size_t)4 * 16 * 32 * 16384;  // 33554432
  const size_t FC_ELEMS = (size_t)16 * 16 * 4096;       // 1048576
  const size_t XBF      = BH;                            // x as bf16
  const size_t MID_BYTES  = (WT_ELEMS + FC_ELEMS) * 2;
  const size_t FULL_BYTES = (WT_ELEMS + FC_ELEMS + XBF + 8 * BH) * 2;

  unsigned short* wt      = (unsigned short*)d_ws;
  unsigned short* fcwt    = wt + WT_ELEMS;
  unsigned short* xbf     = fcwt + FC_ELEMS;
  unsigned short* hprevbf = xbf + XBF;
  unsigned short* houtbf  = hprevbf + 4 * BH;

  const int mode = (ws_size >= FULL_BYTES) ? 2 : (ws_size >= MID_BYTES) ? 1 : 0;

  dim3 blk(NT);
  if (mode >= 1) {
    transposeW<<<dim3(16, 32, 4), blk, 0, stream>>>(Wi, Wh, wt);
    transposeFc<<<dim3(16, 16), blk, 0, stream>>>(fcW, fcwt);
  }
  if (mode == 2) {
    cvt_bf16<<<dim3((int)(XBF / 8 / 256)), dim3(256), 0, stream>>>(x, xbf,
                                                                   (int)(XBF / 8));
    cvt_bf16<<<dim3((int)(4 * BH / 8 / 256)), dim3(256), 0, stream>>>(
        hprev, hprevbf, (int)(4 * BH / 8));
  }

  dim3 grid(512);
  for (int l = 0; l < NLAY; ++l) {
    const float* xin = (l == 0) ? x : (hout + (size_t)(l - 1) * BH);
    const unsigned short* aX =
        (l == 0) ? xbf : (houtbf + (size_t)(l - 1) * BH);
    const unsigned short* wtl = wt + (size_t)l * 16 * 32 * 16384;
    const float* hp = hprev + (size_t)l * BH;
    const float* cp = cprev + (size_t)l * BH;
    float* ho = hout + (size_t)l * BH;
    float* co = cout + (size_t)l * BH;
    if (mode == 2)
      lstm_layer<2><<<grid, blk, 0, stream>>>(
          xin, hp, cp, Wi + (size_t)l * 1024 * 4096, Wh + (size_t)l * 1024 * 4096,
          bi + l * 4096, bh + l * 4096, wtl, aX, hprevbf + (size_t)l * BH,
          ho, co, houtbf + (size_t)l * BH);
    else if (mode == 1)
      lstm_layer<1><<<grid, blk, 0, stream>>>(
          xin, hp, cp, Wi + (size_t)l * 1024 * 4096, Wh + (size_t)l * 1024 * 4096,
          bi + l * 4096, bh + l * 4096, wtl, nullptr, nullptr, ho, co, nullptr);
    else
      lstm_layer<0><<<grid, blk, 0, stream>>>(
          xin, hp, cp, Wi + (size_t)l * 1024 * 4096, Wh + (size_t)l * 1024 * 4096,
          bi + l * 4096, bh + l * 4096, nullptr, nullptr, nullptr, ho, co, nullptr);
  }
  if (mode == 2)
    fc_kernel<2><<<grid, blk, 0, stream>>>(hout + 3 * BH, fcW, fcwt,
                                           houtbf + 3 * BH, fcb, y);
  else if (mode == 1)
    fc_kernel<1><<<grid, blk, 0, stream>>>(hout + 3 * BH, fcW, fcwt, nullptr,
                                           fcb, y);
  else
    fc_kernel<0><<<grid, blk, 0, stream>>>(hout + 3 * BH, fcW, nullptr, nullptr,
                                           fcb, y);
}

// Round 3
// 434.177 us; speedup vs baseline: 1.5510x; 1.4478x over previous
//
#include <hip/hip_runtime.h>

#define B_    4096
#define H_    1024
#define NLAY  4
#define NK    32          // K-tiles of 64 in 2048
#define NT512 512

typedef __attribute__((ext_vector_type(8))) short bf16x8;
typedef __attribute__((ext_vector_type(4))) float f32x4;
typedef unsigned short ushort_t;

__device__ __forceinline__ ushort_t f2bf(float f) {
  unsigned u = __builtin_bit_cast(unsigned, f);
  u += 0x7FFFu + ((u >> 16) & 1u);
  return (ushort_t)(u >> 16);
}

__device__ __forceinline__ float fast_sigmoid(float x) {
  float e = __expf(-fabsf(x));
  float s = 1.0f / (1.0f + e);
  return x >= 0.0f ? s : 1.0f - s;
}
__device__ __forceinline__ float fast_tanh(float x) {
  float e = __expf(-2.0f * fabsf(x));
  float t = (1.0f - e) / (1.0f + e);
  return x >= 0.0f ? t : -t;
}

#define GLDS16(gsrc, ldst)                                                  \
  __builtin_amdgcn_global_load_lds(                                         \
      (__attribute__((address_space(1))) void*)(gsrc),                      \
      (__attribute__((address_space(3))) void*)(ldst), 16, 0, 0)

#define BAR()                                                               \
  { asm volatile("" ::: "memory");                                          \
    __builtin_amdgcn_s_barrier();                                           \
    asm volatile("" ::: "memory"); }

#define WAITV(N)                                                            \
  { asm volatile("s_waitcnt vmcnt(" #N ")" ::: "memory");                   \
    __builtin_amdgcn_sched_barrier(0); }

// ---------------------------------------------------------------------------
// 8-phase fused LSTM layer (m201-style template).
// BM=256 rows x BN=256 packed gate-cols, BK=64, 8 waves (2M x 4N), 512 thr.
// Packed col p = wn*64 + g*16 + hc  <->  gate col g*1024 + bn*64 + wn*16 + hc.
// LDS: 2 dbuf x { A-K0, A-K1, B-K0, B-K1 } halves of 16 KB (256 rows x 32 k).
// Half layout: byte = r*64 + s*16, slot s holds k-octet o = s ^ ((r>>1)&3).
// Per K-tile: 4 phases (kk0/g01, kk0/g23, kk1/g01, kk1/g23), each staging one
// half of tile T+1; counted vmcnt(4) at mid-tile and boundary (drain only at
// the last tile).
// ---------------------------------------------------------------------------
__global__ __launch_bounds__(NT512, 2) void lstm8(
    const ushort_t* __restrict__ aX, const ushort_t* __restrict__ aH,
    const float* __restrict__ cprev, const float* __restrict__ bi,
    const float* __restrict__ bh, const ushort_t* __restrict__ wt,
    float* __restrict__ hout, float* __restrict__ cout,
    ushort_t* __restrict__ hbfout) {
  __shared__ __align__(16) char sL[131072];   // 128 KB

  const int tid  = threadIdx.x;
  const int lane = tid & 63;
  const int wid  = tid >> 6;
  const int wm   = wid >> 2;      // 0..1
  const int wn   = wid & 3;       // 0..3
  const int bid  = (blockIdx.x & 7) * 32 + (blockIdx.x >> 3);  // XCD-chunked
  const int bm   = bid & 15;
  const int bn   = bid >> 4;

  // fragment LDS offsets
  const int fr    = lane & 15;
  const int oF    = lane >> 4;                       // k-octet 0..3
  const int s_    = oF ^ ((fr >> 1) & 3);            // swizzled slot
  const int aBase = (wm * 128 + fr) * 64 + s_ * 16;  // + m*1024
  const int bBase = (wn * 64 + fr) * 64 + s_ * 16;   // + g*1024

  // A-staging per-thread coords (GLDS chunk: q = c*512 + tid)
  const int rA = tid >> 2;
  const int oA = (tid & 3) ^ ((rA >> 1) & 3);
  const size_t aOff = (size_t)(bm * 256 + rA) * 1024 + oA * 8;  // +c*128*1024

  f32x4 acc[8][4];
#pragma unroll
  for (int m = 0; m < 8; ++m)
#pragma unroll
    for (int g = 0; g < 4; ++g) acc[m][g] = (f32x4){0.f, 0.f, 0.f, 0.f};

#define STAGE_A(nb, kt, kh)                                                  \
  {                                                                          \
    const ushort_t* s0 =                                                     \
        (((kt) < 16) ? aX : aH) + aOff + ((kt) & 15) * 64 + (kh) * 32;       \
    GLDS16(s0, sL + (nb)*65536 + (kh)*16384 + wid * 1024);                   \
    GLDS16(s0 + 131072, sL + (nb)*65536 + (kh)*16384 + 8192 + wid * 1024);   \
  }
#define STAGE_B(nb, kt, kh)                                                  \
  {                                                                          \
    const ushort_t* s0 =                                                     \
        wt + ((size_t)(bn * 32 + (kt))) * 16384 + (kh)*8192 + tid * 8;       \
    GLDS16(s0, sL + (nb)*65536 + 32768 + (kh)*16384 + wid * 1024);           \
    GLDS16(s0 + 4096,                                                        \
           sL + (nb)*65536 + 32768 + (kh)*16384 + 8192 + wid * 1024);        \
  }

  // prologue: stage tile 0 (A-K0, B-K0, A-K1, B-K1) into buf 0
  STAGE_A(0, 0, 0);
  STAGE_B(0, 0, 0);
  STAGE_A(0, 0, 1);
  STAGE_B(0, 0, 1);
  WAITV(4);   // A-K0 + B-K0 landed
  BAR();

#pragma unroll 1
  for (int kt = 0; kt < NK; ++kt) {
    const int cb = kt & 1, nb = cb ^ 1;
    const bool st = (kt + 1 < NK);
    const char* pa = sL + cb * 65536;
    const char* pb = sL + cb * 65536 + 32768;

    bf16x8 a[8], bb0, bb1;
    // ---- P1: kk0, gates 0-1 ----
#pragma unroll
    for (int m = 0; m < 8; ++m)
      a[m] = *(const bf16x8*)(pa + aBase + m * 1024);
    bb0 = *(const bf16x8*)(pb + bBase);
    bb1 = *(const bf16x8*)(pb + bBase + 1024);
    if (st) STAGE_A(nb, kt + 1, 0);
    BAR();
    __builtin_amdgcn_s_setprio(1);
#pragma unroll
    for (int m = 0; m < 8; ++m)
      acc[m][0] = __builtin_amdgcn_mfma_f32_16x16x32_bf16(a[m], bb0, acc[m][0], 0, 0, 0);
#pragma unroll
    for (int m = 0; m < 8; ++m)
      acc[m][1] = __builtin_amdgcn_mfma_f32_16x16x32_bf16(a[m], bb1, acc[m][1], 0, 0, 0);
    __builtin_amdgcn_s_setprio(0);
    BAR();
    // ---- P2: kk0, gates 2-3 ----
    bb0 = *(const bf16x8*)(pb + bBase + 2048);
    bb1 = *(const bf16x8*)(pb + bBase + 3072);
    if (st) STAGE_B(nb, kt + 1, 0);
    BAR();
    __builtin_amdgcn_s_setprio(1);
#pragma unroll
    for (int m = 0; m < 8; ++m)
      acc[m][2] = __builtin_amdgcn_mfma_f32_16x16x32_bf16(a[m], bb0, acc[m][2], 0, 0, 0);
#pragma unroll
    for (int m = 0; m < 8; ++m)
      acc[m][3] = __builtin_amdgcn_mfma_f32_16x16x32_bf16(a[m], bb1, acc[m][3], 0, 0, 0);
    __builtin_amdgcn_s_setprio(0);
    if (st) { WAITV(4); } else { WAITV(0); }   // A-K1,B-K1 of this tile landed
    BAR();
    // ---- P3: kk1, gates 0-1 ----
#pragma unroll
    for (int m = 0; m < 8; ++m)
      a[m] = *(const bf16x8*)(pa + 16384 + aBase + m * 1024);
    bb0 = *(const bf16x8*)(pb + 16384 + bBase);
    bb1 = *(const bf16x8*)(pb + 16384 + bBase + 1024);
    if (st) STAGE_A(nb, kt + 1, 1);
    BAR();
    __builtin_amdgcn_s_setprio(1);
#pragma unroll
    for (int m = 0; m < 8; ++m)
      acc[m][0] = __builtin_amdgcn_mfma_f32_16x16x32_bf16(a[m], bb0, acc[m][0], 0, 0, 0);
#pragma unroll
    for (int m = 0; m < 8; ++m)
      acc[m][1] = __builtin_amdgcn_mfma_f32_16x16x32_bf16(a[m], bb1, acc[m][1], 0, 0, 0);
    __builtin_amdgcn_s_setprio(0);
    BAR();
    // ---- P4: kk1, gates 2-3 ----
    bb0 = *(const bf16x8*)(pb + 16384 + bBase + 2048);
    bb1 = *(const bf16x8*)(pb + 16384 + bBase + 3072);
    if (st) STAGE_B(nb, kt + 1, 1);
    BAR();
    __builtin_amdgcn_s_setprio(1);
#pragma unroll
    for (int m = 0; m < 8; ++m)
      acc[m][2] = __builtin_amdgcn_mfma_f32_16x16x32_bf16(a[m], bb0, acc[m][2], 0, 0, 0);
#pragma unroll
    for (int m = 0; m < 8; ++m)
      acc[m][3] = __builtin_amdgcn_mfma_f32_16x16x32_bf16(a[m], bb1, acc[m][3], 0, 0, 0);
    __builtin_amdgcn_s_setprio(0);
    if (st) { WAITV(4); }   // A-K0,B-K0 of tile kt+1 landed
    BAR();
  }
#undef STAGE_A
#undef STAGE_B

  // ---- fused LSTM cell epilogue ----
  const int hcol = bn * 64 + wn * 16 + fr;
  float bsum[4];
#pragma unroll
  for (int g = 0; g < 4; ++g)
    bsum[g] = bi[g * 1024 + hcol] + bh[g * 1024 + hcol];
#pragma unroll
  for (int m = 0; m < 8; ++m) {
    const int row0 = bm * 256 + wm * 128 + m * 16 + (lane >> 4) * 4;
#pragma unroll
    for (int r = 0; r < 4; ++r) {
      const int row = row0 + r;
      const float gi = fast_sigmoid(acc[m][0][r] + bsum[0]);
      const float gf = fast_sigmoid(acc[m][1][r] + bsum[1]);
      const float gg = fast_tanh(acc[m][2][r] + bsum[2]);
      const float go = fast_sigmoid(acc[m][3][r] + bsum[3]);
      const float cp = cprev[(size_t)row * H_ + hcol];
      const float c  = gf * cp + gi * gg;
      const float h  = go * fast_tanh(c);
      cout[(size_t)row * H_ + hcol]   = c;
      hout[(size_t)row * H_ + hcol]   = h;
      hbfout[(size_t)row * H_ + hcol] = f2bf(h);
    }
  }
}

// ---------------------------------------------------------------------------
// Weight pack for lstm8: per (l, bn, ks) a 16384-elem bf16 tile image in the
// exact GLDS-linear order: idx = kh*1024 + r*4 + s, octet o = s ^ ((r>>1)&3),
// holding W[ks*64 + kh*32 + o*8 .. +8][gatecol(p=r)].
// ---------------------------------------------------------------------------
__global__ __launch_bounds__(NT512) void packW(const float* __restrict__ Wi,
                                               const float* __restrict__ Wh,
                                               ushort_t* __restrict__ wt) {
  __shared__ ushort_t t16[64 * 256];   // 32 KB bounce
  const int bn = blockIdx.x;   // 0..15
  const int ks = blockIdx.y;   // 0..31
  const int l  = blockIdx.z;   // 0..3
  const int tid = threadIdx.x;
  const int kq = tid >> 6, cc = tid & 63;
  const int k0 = ks * 64;
  const float* W = (k0 < 1024)
                       ? (Wi + (size_t)l * 1024 * 4096 + (size_t)k0 * 4096)
                       : (Wh + (size_t)l * 1024 * 4096 + (size_t)(k0 - 1024) * 4096);
#pragma unroll
  for (int kk = 0; kk < 8; ++kk) {
    const int kl = kq * 8 + kk;
#pragma unroll
    for (int g = 0; g < 4; ++g) {
      const float v = W[(size_t)kl * 4096 + g * 1024 + bn * 64 + cc];
      const int p = (cc >> 4) * 64 + g * 16 + (cc & 15);
      t16[kl * 256 + p] = f2bf(v);
    }
  }
  __syncthreads();
  ushort_t* tile = wt + (((size_t)l * 16 + bn) * 32 + ks) * 16384;
#pragma unroll
  for (int j = 0; j < 4; ++j) {
    const int idx = j * 512 + tid;          // octet index 0..2047
    const int q = idx & 1023;
    const int r = q >> 2, s = q & 3;
    const int o = s ^ ((r >> 1) & 3);
    const int kl = (idx >> 10) * 32 + o * 8;
    bf16x8 ov;
#pragma unroll
    for (int i = 0; i < 8; ++i) ov[i] = (short)t16[(kl + i) * 256 + r];
    *(bf16x8*)(tile + (size_t)idx * 8) = ov;
  }
}

// ---------------------------------------------------------------------------
// FC path (unchanged 2-phase kernel; ~4% of total work)
// ---------------------------------------------------------------------------
__device__ __forceinline__ int swz(int row, int kelem) {
  return ((row * 64 + kelem) * 2) ^ ((row & 7) << 4);
}

__global__ __launch_bounds__(NT512) void fc_kernel(
    const ushort_t* __restrict__ wtfc, const ushort_t* __restrict__ abf,
    const float* __restrict__ bias, float* __restrict__ y) {
  __shared__ __align__(16) char sA[128 * 64 * 2];
  __shared__ __align__(16) char sB[64 * 64 * 2];
  const int tid  = threadIdx.x;
  const int lane = tid & 63;
  const int wid  = tid >> 6;
  const int wm   = wid >> 2;
  const int wn   = wid & 3;
  const int bid  = (blockIdx.x & 7) * 64 + (blockIdx.x >> 3);
  const int bm   = bid & 31;
  const int bn   = bid >> 5;

  f32x4 acc[4];
#pragma unroll
  for (int m = 0; m < 4; ++m) acc[m] = (f32x4){0.f, 0.f, 0.f, 0.f};

  const int rloc = wid * 8 + (lane >> 3);
  const int jA   = (lane & 7) ^ ((lane >> 3) & 7);
  const ushort_t* aSrc = abf + (size_t)(bm * 128 + rloc) * 1024 + jA * 8;

  for (int ks = 0; ks < 16; ++ks) {
    __syncthreads();
    GLDS16(wtfc + (size_t)(bn * 16 + ks) * 4096 + tid * 8, sB + wid * 1024);
    const int off = ks * 64;
    GLDS16(aSrc + off,             sA + wid * 1024);
    GLDS16(aSrc + off + 64 * 1024, sA + 8192 + wid * 1024);
    __syncthreads();
#pragma unroll
    for (int kk = 0; kk < 64; kk += 32) {
      const int ke = kk + (lane >> 4) * 8;
      bf16x8 a[4];
#pragma unroll
      for (int m = 0; m < 4; ++m)
        a[m] = *(const bf16x8*)(sA + swz(wm * 64 + m * 16 + (lane & 15), ke));
      bf16x8 b = *(const bf16x8*)(sB + swz(wn * 16 + (lane & 15), ke));
#pragma unroll
      for (int m = 0; m < 4; ++m)
        acc[m] = __builtin_amdgcn_mfma_f32_16x16x32_bf16(a[m], b, acc[m], 0, 0, 0);
    }
  }
  const int col = bn * 64 + wn * 16 + (lane & 15);
  const float bb = bias[col];
#pragma unroll
  for (int m = 0; m < 4; ++m) {
    const int row0 = bm * 128 + wm * 64 + m * 16 + ((lane >> 4) << 2);
#pragma unroll
    for (int r = 0; r < 4; ++r)
      y[(size_t)(row0 + r) * 1024 + col] = acc[m][r] + bb;
  }
}

__global__ __launch_bounds__(NT512) void transposeFc(const float* __restrict__ W,
                                                     ushort_t* __restrict__ wt) {
  const int bn = blockIdx.x;   // 0..15
  const int ks = blockIdx.y;   // 0..15
  const int tid = threadIdx.x;
  const int c  = tid & 63;
  const int ko = (tid >> 6) * 8;
  float v[8];
#pragma unroll
  for (int j = 0; j < 8; ++j)
    v[j] = W[(size_t)(ks * 64 + ko + j) * 1024 + bn * 64 + c];
  bf16x8 o;
#pragma unroll
  for (int j = 0; j < 8; ++j) o[j] = (short)f2bf(v[j]);
  ushort_t* tile = wt + ((size_t)bn * 16 + ks) * 4096;
  *(bf16x8*)((char*)tile + swz(c, ko)) = o;
}

// fp32 -> bf16 bulk convert (8 elements/thread)
__global__ __launch_bounds__(256) void cvt_bf16(const float* __restrict__ s,
                                                ushort_t* __restrict__ d,
                                                int n8) {
  const int i = blockIdx.x * 256 + threadIdx.x;
  if (i >= n8) return;
  const float* p = s + (size_t)i * 8;
  f32x4 a = ((const f32x4*)p)[0];
  f32x4 b = ((const f32x4*)p)[1];
  bf16x8 o;
#pragma unroll
  for (int j = 0; j < 4; ++j) {
    o[j]     = (short)f2bf(a[j]);
    o[4 + j] = (short)f2bf(b[j]);
  }
  *(bf16x8*)(d + (size_t)i * 8) = o;
}

extern "C" void kernel_launch(void* const* d_in, const int* in_sizes, int n_in,
                              void* d_out, int out_size, void* d_ws,
                              size_t ws_size, hipStream_t stream) {
  const float* x     = (const float*)d_in[0];
  const float* hprev = (const float*)d_in[1];
  const float* cprev = (const float*)d_in[2];
  const float* Wi    = (const float*)d_in[3];
  const float* Wh    = (const float*)d_in[4];
  const float* bi    = (const float*)d_in[5];
  const float* bh    = (const float*)d_in[6];
  const float* fcW   = (const float*)d_in[7];
  const float* fcb   = (const float*)d_in[8];

  float* out = (float*)d_out;
  const size_t BH = (size_t)B_ * H_;          // 4194304
  float* y    = out;
  float* hout = out + BH;
  float* cout = out + 5 * BH;

  const size_t WT_ELEMS = (size_t)4 * 16 * 32 * 16384;  // 33554432
  const size_t FC_ELEMS = (size_t)16 * 16 * 4096;       // 1048576
  ushort_t* wt      = (ushort_t*)d_ws;
  ushort_t* fcwt    = wt + WT_ELEMS;
  ushort_t* xbf     = fcwt + FC_ELEMS;
  ushort_t* hprevbf = xbf + BH;
  ushort_t* houtbf  = hprevbf + 4 * BH;

  dim3 blk(NT512);
  packW<<<dim3(16, 32, 4), blk, 0, stream>>>(Wi, Wh, wt);
  transposeFc<<<dim3(16, 16), blk, 0, stream>>>(fcW, fcwt);
  cvt_bf16<<<dim3((int)(BH / 8 / 256)), dim3(256), 0, stream>>>(x, xbf,
                                                                (int)(BH / 8));
  cvt_bf16<<<dim3((int)(4 * BH / 8 / 256)), dim3(256), 0, stream>>>(
      hprev, hprevbf, (int)(4 * BH / 8));

  for (int l = 0; l < NLAY; ++l) {
    const ushort_t* aX  = (l == 0) ? xbf : (houtbf + (size_t)(l - 1) * BH);
    const ushort_t* wtl = wt + (size_t)l * 16 * 32 * 16384;
    lstm8<<<dim3(256), blk, 0, stream>>>(
        aX, hprevbf + (size_t)l * BH, cprev + (size_t)l * BH, bi + l * 4096,
        bh + l * 4096, wtl, hout + (size_t)l * BH, cout + (size_t)l * BH,
        houtbf + (size_t)l * BH);
  }
  fc_kernel<<<dim3(512), blk, 0, stream>>>(fcwt, houtbf + 3 * BH, fcb, y);
}

// Round 4
// 391.582 us; speedup vs baseline: 1.7197x; 1.1088x over previous
//
#include <hip/hip_runtime.h>

#define B_    4096
#define H_    1024
#define NLAY  4
#define NT512 512

typedef __attribute__((ext_vector_type(8))) short bf16x8;
typedef __attribute__((ext_vector_type(4))) short s16x4;
typedef __attribute__((ext_vector_type(4))) float f32x4;
typedef unsigned short ushort_t;

__device__ __forceinline__ ushort_t f2bf(float f) {
  unsigned u = __builtin_bit_cast(unsigned, f);
  u += 0x7FFFu + ((u >> 16) & 1u);
  return (ushort_t)(u >> 16);
}

__device__ __forceinline__ float fast_sigmoid(float x) {
  float e = __expf(-fabsf(x));
  float s = 1.0f / (1.0f + e);
  return x >= 0.0f ? s : 1.0f - s;
}
__device__ __forceinline__ float fast_tanh(float x) {
  float e = __expf(-2.0f * fabsf(x));
  float t = (1.0f - e) / (1.0f + e);
  return x >= 0.0f ? t : -t;
}

#define GLDS16(gsrc, ldst)                                                  \
  __builtin_amdgcn_global_load_lds(                                         \
      (__attribute__((address_space(1))) void*)(gsrc),                      \
      (__attribute__((address_space(3))) void*)(ldst), 16, 0, 0)

#define BAR()                                                               \
  { asm volatile("" ::: "memory");                                          \
    __builtin_amdgcn_s_barrier();                                           \
    asm volatile("" ::: "memory"); }

#define WAITV(N)                                                            \
  { asm volatile("s_waitcnt vmcnt(" #N ")" ::: "memory");                   \
    __builtin_amdgcn_sched_barrier(0); }

// ---------------------------------------------------------------------------
// Deep-pipelined fused LSTM layer.
// BM=256 rows x BN=256 packed gate-cols (4 gates x 64 hcols), BK=32,
// 64 K-tiles. 8 waves (2M x 4N), wave tile 128 rows x 16 hcols x 4 gates.
// LDS: 4 buffers x (A 16KB + B 16KB) = 128 KB; prefetch distance 3 tiles.
// Buffer row: 32 k bf16 (64 B), slot s of row r holds k-octet o = s^((r>>1)&3)
// (conflict-free ds_read_b128).  Sync: ONE {vmcnt(8); s_barrier} per tile —
// buffers t, t+1, t+2, t+3 are distinct mod 4, so no intra-tile barriers.
// ---------------------------------------------------------------------------
__global__ __launch_bounds__(NT512, 2) void lstm8(
    const ushort_t* __restrict__ aX, const ushort_t* __restrict__ aH,
    const float* __restrict__ cprev, const float* __restrict__ bi,
    const float* __restrict__ bh, const ushort_t* __restrict__ wt,
    float* __restrict__ hout, float* __restrict__ cout,
    ushort_t* __restrict__ hbfout) {
  __shared__ __align__(16) char sL[131072];   // 128 KB

  const int tid  = threadIdx.x;
  const int lane = tid & 63;
  const int wid  = tid >> 6;
  const int wm   = wid >> 2;      // 0..1
  const int wn   = wid & 3;       // 0..3
  const int bid  = (blockIdx.x & 7) * 32 + (blockIdx.x >> 3);  // XCD-chunked
  const int bm   = bid & 15;
  const int bn   = bid >> 4;

  // fragment LDS offsets
  const int fr    = lane & 15;
  const int oF    = lane >> 4;                       // k-octet 0..3
  const int s_    = oF ^ ((fr >> 1) & 3);            // swizzled slot
  const int aBase = (wm * 128 + fr) * 64 + s_ * 16;  // + m*1024
  const int bBase = (wn * 64 + fr) * 64 + s_ * 16;   // + g*1024

  // A-staging per-thread source coords (GLDS: lds byte = tid*16 [+8192])
  const int rA = tid >> 2;
  const int oA = (tid & 3) ^ ((rA >> 1) & 3);
  const size_t aOff = (size_t)(bm * 256 + rA) * 1024 + oA * 8;

  const ushort_t* wtBn = wt + (size_t)bn * 64 * 8192;

  f32x4 acc[8][4];
#pragma unroll
  for (int m = 0; m < 8; ++m)
#pragma unroll
    for (int g = 0; g < 4; ++g) acc[m][g] = (f32x4){0.f, 0.f, 0.f, 0.f};

  // ---- prologue: stage tiles 0,1,2 into buffers 0,1,2 (4 loads each) ----
#pragma unroll
  for (int t = 0; t < 3; ++t) {
    const ushort_t* s0 = aX + aOff + t * 32;          // tiles 0..2 are x-region
    GLDS16(s0,          sL + t * 32768 + wid * 1024);
    GLDS16(s0 + 131072, sL + t * 32768 + 8192 + wid * 1024);
    const ushort_t* sb = wtBn + (size_t)t * 8192 + tid * 8;
    GLDS16(sb,        sL + t * 32768 + 16384 + wid * 1024);
    GLDS16(sb + 4096, sL + t * 32768 + 16384 + 8192 + wid * 1024);
  }
  WAITV(8);   // tile 0's 4 loads landed
  BAR();

#define TSTEP(BUFC, T, ISSUE)                                                \
  {                                                                          \
    const char* pa = sL + (BUFC) * 32768;                                    \
    const char* pb = pa + 16384;                                             \
    char* nbuf = sL + (((BUFC) + 3) & 3) * 32768;                            \
    bf16x8 a[8], b0, b1;                                                     \
    _Pragma("unroll")                                                        \
    for (int m = 0; m < 8; ++m)                                              \
      a[m] = *(const bf16x8*)(pa + aBase + m * 1024);                        \
    b0 = *(const bf16x8*)(pb + bBase);                                       \
    b1 = *(const bf16x8*)(pb + bBase + 1024);                                \
    if (ISSUE) {                                                             \
      const int tt = (T) + 3;                                                \
      const ushort_t* s0 = (tt < 32 ? aX : aH) + (aOff + (tt & 31) * 32);    \
      GLDS16(s0,          nbuf + wid * 1024);                                \
      GLDS16(s0 + 131072, nbuf + 8192 + wid * 1024);                         \
    }                                                                        \
    __builtin_amdgcn_s_setprio(1);                                           \
    _Pragma("unroll")                                                        \
    for (int m = 0; m < 8; ++m)                                              \
      acc[m][0] =                                                            \
          __builtin_amdgcn_mfma_f32_16x16x32_bf16(a[m], b0, acc[m][0], 0, 0, 0); \
    _Pragma("unroll")                                                        \
    for (int m = 0; m < 8; ++m)                                              \
      acc[m][1] =                                                            \
          __builtin_amdgcn_mfma_f32_16x16x32_bf16(a[m], b1, acc[m][1], 0, 0, 0); \
    __builtin_amdgcn_s_setprio(0);                                           \
    bf16x8 b2 = *(const bf16x8*)(pb + bBase + 2048);                         \
    bf16x8 b3 = *(const bf16x8*)(pb + bBase + 3072);                         \
    if (ISSUE) {                                                             \
      const int tt = (T) + 3;                                                \
      const ushort_t* sb = wtBn + (size_t)tt * 8192 + tid * 8;               \
      GLDS16(sb,        nbuf + 16384 + wid * 1024);                          \
      GLDS16(sb + 4096, nbuf + 16384 + 8192 + wid * 1024);                   \
    }                                                                        \
    __builtin_amdgcn_s_setprio(1);                                           \
    _Pragma("unroll")                                                        \
    for (int m = 0; m < 8; ++m)                                              \
      acc[m][2] =                                                            \
          __builtin_amdgcn_mfma_f32_16x16x32_bf16(a[m], b2, acc[m][2], 0, 0, 0); \
    _Pragma("unroll")                                                        \
    for (int m = 0; m < 8; ++m)                                              \
      acc[m][3] =                                                            \
          __builtin_amdgcn_mfma_f32_16x16x32_bf16(a[m], b3, acc[m][3], 0, 0, 0); \
    __builtin_amdgcn_s_setprio(0);                                           \
  }

#pragma unroll 1
  for (int t = 0; t < 60; t += 4) {
    TSTEP(0, t + 0, 1) WAITV(8); BAR();
    TSTEP(1, t + 1, 1) WAITV(8); BAR();
    TSTEP(2, t + 2, 1) WAITV(8); BAR();
    TSTEP(3, t + 3, 1) WAITV(8); BAR();
  }
  TSTEP(0, 60, 1) WAITV(8); BAR();
  TSTEP(1, 61, 0) WAITV(4); BAR();
  TSTEP(2, 62, 0) WAITV(0); BAR();
  TSTEP(3, 63, 0)
#undef TSTEP

  // ---- epilogue: LSTM cell + coalesced stores via padded LDS bounce ----
  const int hcolL = wn * 16 + fr;              // 0..63
  const int hcol  = bn * 64 + hcolL;
  float bsum[4];
#pragma unroll
  for (int g = 0; g < 4; ++g)
    bsum[g] = bi[g * 1024 + hcol] + bh[g * 1024 + hcol];

#define LSTRIDE 68
  float* LF = (float*)sL;
  const int crow = (tid >> 4);          // coop row within group of 32
  const int cc4  = (tid & 15) * 4;      // coop col (x4)
  BAR();   // K-loop LDS dead everywhere
  // coop-load cprev tile (coalesced)
  {
    const float* cp0 = cprev + (size_t)(bm * 256) * 1024 + bn * 64;
#pragma unroll
    for (int i = 0; i < 8; ++i) {
      const int row = i * 32 + crow;
      f32x4 v = *(const f32x4*)(cp0 + (size_t)row * 1024 + cc4);
      *(f32x4*)(LF + row * LSTRIDE + cc4) = v;
    }
  }
  BAR();
  float cv[8][4], hv[8][4];
#pragma unroll
  for (int m = 0; m < 8; ++m) {
    const int rowb = wm * 128 + m * 16 + oF * 4;
#pragma unroll
    for (int r = 0; r < 4; ++r) {
      const float cp = LF[(rowb + r) * LSTRIDE + hcolL];
      const float gi = fast_sigmoid(acc[m][0][r] + bsum[0]);
      const float gf = fast_sigmoid(acc[m][1][r] + bsum[1]);
      const float gg = fast_tanh(acc[m][2][r] + bsum[2]);
      const float go = fast_sigmoid(acc[m][3][r] + bsum[3]);
      const float c  = gf * cp + gi * gg;
      cv[m][r] = c;
      hv[m][r] = go * fast_tanh(c);
    }
  }
  BAR();   // all cprev reads done before overwrite
#pragma unroll
  for (int m = 0; m < 8; ++m) {
    const int rowb = wm * 128 + m * 16 + oF * 4;
#pragma unroll
    for (int r = 0; r < 4; ++r) LF[(rowb + r) * LSTRIDE + hcolL] = cv[m][r];
  }
  BAR();
  {
    float* co0 = cout + (size_t)(bm * 256) * 1024 + bn * 64;
#pragma unroll
    for (int i = 0; i < 8; ++i) {
      const int row = i * 32 + crow;
      f32x4 v = *(const f32x4*)(LF + row * LSTRIDE + cc4);
      *(f32x4*)(co0 + (size_t)row * 1024 + cc4) = v;
    }
  }
  BAR();
#pragma unroll
  for (int m = 0; m < 8; ++m) {
    const int rowb = wm * 128 + m * 16 + oF * 4;
#pragma unroll
    for (int r = 0; r < 4; ++r) LF[(rowb + r) * LSTRIDE + hcolL] = hv[m][r];
  }
  BAR();
  {
    float* ho0 = hout + (size_t)(bm * 256) * 1024 + bn * 64;
    ushort_t* hb0 = hbfout + (size_t)(bm * 256) * 1024 + bn * 64;
#pragma unroll
    for (int i = 0; i < 8; ++i) {
      const int row = i * 32 + crow;
      f32x4 v = *(const f32x4*)(LF + row * LSTRIDE + cc4);
      *(f32x4*)(ho0 + (size_t)row * 1024 + cc4) = v;
      s16x4 hb;
#pragma unroll
      for (int j = 0; j < 4; ++j) hb[j] = (short)f2bf(v[j]);
      *(s16x4*)(hb0 + (size_t)row * 1024 + cc4) = hb;
    }
  }
#undef LSTRIDE
}

// ---------------------------------------------------------------------------
// Weight pack: per (l, bn, kt[0..63]) an 8192-elem bf16 tile, linear GLDS
// image: octet q: r=q>>2, s=q&3, o=s^((r>>1)&3), k = kt*32 + o*8..+8,
// packed col r -> gate col ((r>>4)&3)*1024 + bn*64 + (r>>6)*16 + (r&15).
// ---------------------------------------------------------------------------
__global__ __launch_bounds__(NT512) void packW(const float* __restrict__ Wi,
                                               const float* __restrict__ Wh,
                                               ushort_t* __restrict__ wt) {
  __shared__ ushort_t t16[64 * 256];   // 32 KB bounce: [kl][packed col]
  const int bn = blockIdx.x;   // 0..15
  const int kb = blockIdx.y;   // 0..31 (64-k chunks)
  const int l  = blockIdx.z;   // 0..3
  const int tid = threadIdx.x;
  const int kq = tid >> 6, cc = tid & 63;
  const int k0 = kb * 64;
  const float* W = (k0 < 1024)
                       ? (Wi + (size_t)l * 1024 * 4096 + (size_t)k0 * 4096)
                       : (Wh + (size_t)l * 1024 * 4096 + (size_t)(k0 - 1024) * 4096);
#pragma unroll
  for (int kk = 0; kk < 8; ++kk) {
    const int kl = kq * 8 + kk;
#pragma unroll
    for (int g = 0; g < 4; ++g) {
      const float v = W[(size_t)kl * 4096 + g * 1024 + bn * 64 + cc];
      const int p = (cc >> 4) * 64 + g * 16 + (cc & 15);
      t16[kl * 256 + p] = f2bf(v);
    }
  }
  __syncthreads();
#pragma unroll
  for (int half = 0; half < 2; ++half) {
    ushort_t* tile =
        wt + (((size_t)l * 16 + bn) * 64 + kb * 2 + half) * 8192;
#pragma unroll
    for (int j = 0; j < 2; ++j) {
      const int q = j * 512 + tid;          // octet 0..1023
      const int r = q >> 2, s = q & 3;
      const int o = s ^ ((r >> 1) & 3);
      const int kl = half * 32 + o * 8;
      bf16x8 ov;
#pragma unroll
      for (int i = 0; i < 8; ++i) ov[i] = (short)t16[(kl + i) * 256 + r];
      *(bf16x8*)(tile + (size_t)q * 8) = ov;
    }
  }
}

// ---------------------------------------------------------------------------
// FC path (2-phase; ~4% of total work)
// ---------------------------------------------------------------------------
__device__ __forceinline__ int swz(int row, int kelem) {
  return ((row * 64 + kelem) * 2) ^ ((row & 7) << 4);
}

__global__ __launch_bounds__(NT512) void fc_kernel(
    const ushort_t* __restrict__ wtfc, const ushort_t* __restrict__ abf,
    const float* __restrict__ bias, float* __restrict__ y) {
  __shared__ __align__(16) char sA[128 * 64 * 2];
  __shared__ __align__(16) char sB[64 * 64 * 2];
  const int tid  = threadIdx.x;
  const int lane = tid & 63;
  const int wid  = tid >> 6;
  const int wm   = wid >> 2;
  const int wn   = wid & 3;
  const int bid  = (blockIdx.x & 7) * 64 + (blockIdx.x >> 3);
  const int bm   = bid & 31;
  const int bn   = bid >> 5;

  f32x4 acc[4];
#pragma unroll
  for (int m = 0; m < 4; ++m) acc[m] = (f32x4){0.f, 0.f, 0.f, 0.f};

  const int rloc = wid * 8 + (lane >> 3);
  const int jA   = (lane & 7) ^ ((lane >> 3) & 7);
  const ushort_t* aSrc = abf + (size_t)(bm * 128 + rloc) * 1024 + jA * 8;

  for (int ks = 0; ks < 16; ++ks) {
    __syncthreads();
    GLDS16(wtfc + (size_t)(bn * 16 + ks) * 4096 + tid * 8, sB + wid * 1024);
    const int off = ks * 64;
    GLDS16(aSrc + off,             sA + wid * 1024);
    GLDS16(aSrc + off + 64 * 1024, sA + 8192 + wid * 1024);
    __syncthreads();
#pragma unroll
    for (int kk = 0; kk < 64; kk += 32) {
      const int ke = kk + (lane >> 4) * 8;
      bf16x8 a[4];
#pragma unroll
      for (int m = 0; m < 4; ++m)
        a[m] = *(const bf16x8*)(sA + swz(wm * 64 + m * 16 + (lane & 15), ke));
      bf16x8 b = *(const bf16x8*)(sB + swz(wn * 16 + (lane & 15), ke));
#pragma unroll
      for (int m = 0; m < 4; ++m)
        acc[m] = __builtin_amdgcn_mfma_f32_16x16x32_bf16(a[m], b, acc[m], 0, 0, 0);
    }
  }
  const int col = bn * 64 + wn * 16 + (lane & 15);
  const float bb = bias[col];
#pragma unroll
  for (int m = 0; m < 4; ++m) {
    const int row0 = bm * 128 + wm * 64 + m * 16 + ((lane >> 4) << 2);
#pragma unroll
    for (int r = 0; r < 4; ++r)
      y[(size_t)(row0 + r) * 1024 + col] = acc[m][r] + bb;
  }
}

__global__ __launch_bounds__(NT512) void transposeFc(const float* __restrict__ W,
                                                     ushort_t* __restrict__ wt) {
  const int bn = blockIdx.x;   // 0..15
  const int ks = blockIdx.y;   // 0..15
  const int tid = threadIdx.x;
  const int c  = tid & 63;
  const int ko = (tid >> 6) * 8;
  float v[8];
#pragma unroll
  for (int j = 0; j < 8; ++j)
    v[j] = W[(size_t)(ks * 64 + ko + j) * 1024 + bn * 64 + c];
  bf16x8 o;
#pragma unroll
  for (int j = 0; j < 8; ++j) o[j] = (short)f2bf(v[j]);
  ushort_t* tile = wt + ((size_t)bn * 16 + ks) * 4096;
  *(bf16x8*)((char*)tile + swz(c, ko)) = o;
}

// fp32 -> bf16 bulk convert (8 elements/thread)
__global__ __launch_bounds__(256) void cvt_bf16(const float* __restrict__ s,
                                                ushort_t* __restrict__ d,
                                                int n8) {
  const int i = blockIdx.x * 256 + threadIdx.x;
  if (i >= n8) return;
  const float* p = s + (size_t)i * 8;
  f32x4 a = ((const f32x4*)p)[0];
  f32x4 b = ((const f32x4*)p)[1];
  bf16x8 o;
#pragma unroll
  for (int j = 0; j < 4; ++j) {
    o[j]     = (short)f2bf(a[j]);
    o[4 + j] = (short)f2bf(b[j]);
  }
  *(bf16x8*)(d + (size_t)i * 8) = o;
}

extern "C" void kernel_launch(void* const* d_in, const int* in_sizes, int n_in,
                              void* d_out, int out_size, void* d_ws,
                              size_t ws_size, hipStream_t stream) {
  const float* x     = (const float*)d_in[0];
  const float* hprev = (const float*)d_in[1];
  const float* cprev = (const float*)d_in[2];
  const float* Wi    = (const float*)d_in[3];
  const float* Wh    = (const float*)d_in[4];
  const float* bi    = (const float*)d_in[5];
  const float* bh    = (const float*)d_in[6];
  const float* fcW   = (const float*)d_in[7];
  const float* fcb   = (const float*)d_in[8];

  float* out = (float*)d_out;
  const size_t BH = (size_t)B_ * H_;          // 4194304
  float* y    = out;
  float* hout = out + BH;
  float* cout = out + 5 * BH;

  const size_t WT_ELEMS = (size_t)4 * 16 * 64 * 8192;   // 33554432
  const size_t FC_ELEMS = (size_t)16 * 16 * 4096;       // 1048576
  ushort_t* wt      = (ushort_t*)d_ws;
  ushort_t* fcwt    = wt + WT_ELEMS;
  ushort_t* xbf     = fcwt + FC_ELEMS;
  ushort_t* hprevbf = xbf + BH;
  ushort_t* houtbf  = hprevbf + 4 * BH;

  dim3 blk(NT512);
  packW<<<dim3(16, 32, 4), blk, 0, stream>>>(Wi, Wh, wt);
  transposeFc<<<dim3(16, 16), blk, 0, stream>>>(fcW, fcwt);
  cvt_bf16<<<dim3((int)(BH / 8 / 256)), dim3(256), 0, stream>>>(x, xbf,
                                                                (int)(BH / 8));
  cvt_bf16<<<dim3((int)(4 * BH / 8 / 256)), dim3(256), 0, stream>>>(
      hprev, hprevbf, (int)(4 * BH / 8));

  for (int l = 0; l < NLAY; ++l) {
    const ushort_t* aX  = (l == 0) ? xbf : (houtbf + (size_t)(l - 1) * BH);
    const ushort_t* wtl = wt + (size_t)l * 16 * 64 * 8192;
    lstm8<<<dim3(256), blk, 0, stream>>>(
        aX, hprevbf + (size_t)l * BH, cprev + (size_t)l * BH, bi + l * 4096,
        bh + l * 4096, wtl, hout + (size_t)l * BH, cout + (size_t)l * BH,
        houtbf + (size_t)l * BH);
  }
  fc_kernel<<<dim3(512), blk, 0, stream>>>(fcwt, houtbf + 3 * BH, fcb, y);
}